// Round 3
// baseline (1516.306 us; speedup 1.0000x reference)
//
#include <hip/hip_runtime.h>
#include <stdint.h>

// LSTM2Encoder: x=emb[ids]; h0=lstm0(x); h1=lstm1(h0); out=relu(h1@Wlin^T+b)
// f-gate eliminated (c_prev=0). Per layer: ig-GEMM (N=1024, (i,g)-interleaved,
// epilogue t=tanh(sig(i)tanh(g)) -> int16) then o-GEMM (N=512, h=sig(o)*t).
// A staged as raw fp32 (or int16 for the last GEMM), split to bf16 hi/lo
// in-register (RTZ, 3 VALU/elem); layer-0 A gathers emb rows via ids directly
// in global_load_lds (global side is per-lane; only LDS dest is lane-locked).
// B pre-split RNE bf16 hi/lo at prep. 3-product split MFMA f32_16x16x32_bf16.

typedef unsigned short ushort_t;
typedef __attribute__((ext_vector_type(8))) short short8;
typedef __attribute__((ext_vector_type(4))) float float4v;

union SU { short8 s; unsigned int u[4]; };

__device__ __forceinline__ ushort_t f2bf(float x) {   // RNE (prep only)
  union { float f; unsigned int u; } a; a.f = x;
  unsigned int r = a.u + 0x7fffu + ((a.u >> 16) & 1u);
  return (ushort_t)(r >> 16);
}
__device__ __forceinline__ float bf2f(ushort_t h) {
  union { unsigned int u; float f; } a; a.u = ((unsigned int)h) << 16;
  return a.f;
}
__device__ __forceinline__ float sigmoidf_(float x) { return 1.0f / (1.0f + __expf(-x)); }
__device__ __forceinline__ float tanhf_(float x) { return 1.0f - 2.0f / (__expf(2.0f * x) + 1.0f); }

__device__ __forceinline__ short q16(float t) {
  float s = fminf(fmaxf(t * 32768.0f, -32767.0f), 32767.0f);
  return (short)__float2int_rn(s);
}

__device__ __forceinline__ void gl2lds16(const void* g, void* l) {
  __builtin_amdgcn_global_load_lds(
      (const __attribute__((address_space(1))) void*)g,
      (__attribute__((address_space(3))) void*)l, 16, 0, 0);
}

// pack hi16 of two f32 words: D = (hi16(ub)<<16)|hi16(ua)  (1 v_perm_b32)
__device__ __forceinline__ unsigned pk_hi16(unsigned ub, unsigned ua) {
  return __builtin_amdgcn_perm(ub, ua, 0x07060302u);
}
// RTZ hi/lo bf16 split of a float pair (6 VALU per 2 elems)
__device__ __forceinline__ void splitpair(float fa, float fb, unsigned& h, unsigned& l) {
  unsigned ua = __float_as_uint(fa), ub = __float_as_uint(fb);
  h = pk_hi16(ub, ua);
  float ra = fa - __uint_as_float(ua & 0xffff0000u);
  float rb = fb - __uint_as_float(ub & 0xffff0000u);
  l = pk_hi16(__float_as_uint(rb), __float_as_uint(ra));
}
__device__ __forceinline__ void split8(const float* f, short8& h, short8& l) {
  SU H, L;
#pragma unroll
  for (int e = 0; e < 4; ++e) splitpair(f[2 * e], f[2 * e + 1], H.u[e], L.u[e]);
  h = H.s; l = L.s;
}

// ---------------- prep: permute+split weights, fold biases -----------------
// Wig rows: n' = 2u+g' -> orig row u + g'*1024 (gates i,g). Wo: orig 1536+u.
__global__ __launch_bounds__(256) void prep_kernel(
    const float* __restrict__ W0, const float* __restrict__ bi0, const float* __restrict__ bh0,
    const float* __restrict__ W1, const float* __restrict__ bi1, const float* __restrict__ bh1,
    const float* __restrict__ WL,
    ushort_t* __restrict__ Wig0h, ushort_t* __restrict__ Wig0l,
    ushort_t* __restrict__ Wo0h,  ushort_t* __restrict__ Wo0l,
    ushort_t* __restrict__ Wig1h, ushort_t* __restrict__ Wig1l,
    ushort_t* __restrict__ Wo1h,  ushort_t* __restrict__ Wo1l,
    ushort_t* __restrict__ WLh,   ushort_t* __restrict__ WLl,
    float* __restrict__ big0, float* __restrict__ bo0,
    float* __restrict__ big1, float* __restrict__ bo1)
{
  int id = blockIdx.x * 256 + threadIdx.x;
  if (id < 524288) {                       // Wig0
    int n = id >> 9, k = id & 511;
    int orig = (n >> 1) + (n & 1) * 1024;
    float v = W0[orig * 512 + k];
    ushort_t h = f2bf(v); Wig0h[id] = h; Wig0l[id] = f2bf(v - bf2f(h));
  } else if (id < 786432) {                // Wo0
    int f = id - 524288; int n = f >> 9, k = f & 511;
    float v = W0[(1536 + n) * 512 + k];
    ushort_t h = f2bf(v); Wo0h[f] = h; Wo0l[f] = f2bf(v - bf2f(h));
  } else if (id < 1310720) {               // Wig1
    int f = id - 786432; int n = f >> 9, k = f & 511;
    int orig = (n >> 1) + (n & 1) * 1024;
    float v = W1[orig * 512 + k];
    ushort_t h = f2bf(v); Wig1h[f] = h; Wig1l[f] = f2bf(v - bf2f(h));
  } else if (id < 1572864) {               // Wo1
    int f = id - 1310720; int n = f >> 9, k = f & 511;
    float v = W1[(1536 + n) * 512 + k];
    ushort_t h = f2bf(v); Wo1h[f] = h; Wo1l[f] = f2bf(v - bf2f(h));
  } else if (id < 1835008) {               // WL
    int f = id - 1572864;
    float v = WL[f];
    ushort_t h = f2bf(v); WLh[f] = h; WLl[f] = f2bf(v - bf2f(h));
  } else if (id < 1836032) {               // big0
    int n = id - 1835008;
    int orig = (n >> 1) + (n & 1) * 1024;
    big0[n] = bi0[orig] + bh0[orig];
  } else if (id < 1836544) {               // bo0
    int n = id - 1836032;
    bo0[n] = bi0[1536 + n] + bh0[1536 + n];
  } else if (id < 1837568) {               // big1
    int n = id - 1836544;
    int orig = (n >> 1) + (n & 1) * 1024;
    big1[n] = bi1[orig] + bh1[orig];
  } else if (id < 1838080) {               // bo1
    int n = id - 1837568;
    bo1[n] = bi1[1536 + n] + bh1[1536 + n];
  }
}

// ---------------- fused split-GEMM, 256x128 tile, BK=32 --------------------
// AMODE 0: A rows are fp32 (optionally gathered via ids);  1: A rows int16.
// EMODE 0: ig -> t=tanh(sig(i)tanh(g)) int16      (N=1024, pair-interleaved)
//       1: o  -> H fp32 = sig(o)*t                 (N=512)
//       2: o  -> int16 in-place over t             (N=512)
//       3: linear -> Out fp32 = relu(acc+bias)     (N=512)
template <int AMODE, int EMODE>
__global__ __launch_bounds__(512, 4) void gemm_kernel(
    const void* __restrict__ Av, const int* __restrict__ ids,
    const ushort_t* __restrict__ Bh, const ushort_t* __restrict__ Bl,
    const float* __restrict__ bias,
    short* __restrict__ Tq, float* __restrict__ Hf, float* __restrict__ Out,
    int nbShift, int nbMask)
{
  __shared__ __align__(16) char smem[49152];        // 48 KB
  float*    sAf = (float*)smem;                     // 256 x 32 fp32 (AMODE 0)
  short*    sAq = (short*)smem;                     // 256 x 32 i16  (AMODE 1)
  ushort_t* sBh = (ushort_t*)(smem + 32768);        // 128 x 32 bf16
  ushort_t* sBl = (ushort_t*)(smem + 40960);

  const int T = threadIdx.x;
  const int lane = T & 63;
  const int wv = T >> 6;
  const int wrow = wv >> 1, wcol = wv & 1;          // 4 x 2 wave grid
  const int mb = (int)blockIdx.x >> nbShift;
  const int nb = (int)blockIdx.x & nbMask;
  const size_t t0 = (size_t)mb * 256;
  const int n0 = nb * 128;

  // ---- B staging (R2-proven): LDS chunk T <- global chunk qgB of row rB
  const int rB = T >> 2;
  const int qgB = (T & 3) ^ ((rB >> 1) & 3);
  const int loB = T * 8;
  const ushort_t* gBh = Bh + (size_t)(n0 + rB) * 512 + qgB * 8;
  const ushort_t* gBl = Bl + (size_t)(n0 + rB) * 512 + qgB * 8;

  // ---- A staging offsets (element units; +32 per iter)
  size_t rowoff[4];
  if (AMODE == 0) {
    const int rl = T >> 3;                          // 0..63
    const int cg = (T & 7) ^ (rl & 7);              // 16B-chunk XOR swizzle
#pragma unroll
    for (int q = 0; q < 4; ++q) {
      size_t row = t0 + q * 64 + rl;
      size_t src = ids ? (size_t)ids[row] : row;
      rowoff[q] = src * 512 + (size_t)cg * 4;
    }
  } else {
    const int rl = T >> 2;                          // 0..127
    const int cg = (T & 3) ^ (rl & 3);
#pragma unroll
    for (int q = 0; q < 2; ++q)
      rowoff[q] = (t0 + q * 128 + rl) * 512 + (size_t)cg * 8;
  }
  const float* Af = (const float*)Av;
  const short* Aq = (const short*)Av;

  // ---- fragment read offsets
  const int m_ = lane & 15, qf = lane >> 4;
  const int qsB = qf ^ ((m_ >> 1) & 3);
  const int offB = wcol * 2048 + m_ * 32 + qsB * 8;

  float4v acc[4][4];
#pragma unroll
  for (int i = 0; i < 4; ++i)
#pragma unroll
    for (int j = 0; j < 4; ++j)
      acc[i][j] = (float4v){0.f, 0.f, 0.f, 0.f};

  for (int it = 0; it < 16; ++it) {
    if (AMODE == 0) {
      gl2lds16(Af + rowoff[0] + it * 32, sAf + T * 4);
      gl2lds16(Af + rowoff[1] + it * 32, sAf + 2048 + T * 4);
      gl2lds16(Af + rowoff[2] + it * 32, sAf + 4096 + T * 4);
      gl2lds16(Af + rowoff[3] + it * 32, sAf + 6144 + T * 4);
    } else {
      gl2lds16(Aq + rowoff[0] + it * 32, sAq + T * 8);
      gl2lds16(Aq + rowoff[1] + it * 32, sAq + 4096 + T * 8);
    }
    gl2lds16(gBh, sBh + loB);
    gl2lds16(gBl, sBl + loB);
    gBh += 32; gBl += 32;
    __syncthreads();

    short8 aH[4], aL[4], bH[4], bL[4];
#pragma unroll
    for (int i = 0; i < 4; ++i) {
      bH[i] = *(const short8*)(sBh + offB + i * 512);
      bL[i] = *(const short8*)(sBl + offB + i * 512);
      if (AMODE == 0) {
        const int base = (wrow * 64 + i * 16 + m_) * 32;
        float4v x0 = *(const float4v*)(sAf + base + (((2 * qf)     ^ (m_ & 7)) * 4));
        float4v x1 = *(const float4v*)(sAf + base + (((2 * qf + 1) ^ (m_ & 7)) * 4));
        float f[8] = {x0[0], x0[1], x0[2], x0[3], x1[0], x1[1], x1[2], x1[3]};
        split8(f, aH[i], aL[i]);
      } else {
        short8 q = *(const short8*)(sAq + (wrow * 64 + i * 16 + m_) * 32 + (qf ^ (m_ & 3)) * 8);
        float f[8];
#pragma unroll
        for (int e = 0; e < 8; ++e) f[e] = (float)q[e] * (1.0f / 32768.0f);
        split8(f, aH[i], aL[i]);
      }
    }
#pragma unroll
    for (int i = 0; i < 4; ++i)
#pragma unroll
      for (int j = 0; j < 4; ++j) {
        acc[i][j] = __builtin_amdgcn_mfma_f32_16x16x32_bf16(aH[i], bH[j], acc[i][j], 0, 0, 0);
        acc[i][j] = __builtin_amdgcn_mfma_f32_16x16x32_bf16(aL[i], bH[j], acc[i][j], 0, 0, 0);
        acc[i][j] = __builtin_amdgcn_mfma_f32_16x16x32_bf16(aH[i], bL[j], acc[i][j], 0, 0, 0);
      }
    __syncthreads();
  }

  float biasv[4];
#pragma unroll
  for (int j = 0; j < 4; ++j) biasv[j] = bias[n0 + wcol * 64 + j * 16 + m_];

  if (EMODE == 0) {
    const bool odd = (m_ & 1) != 0;
#pragma unroll
    for (int i = 0; i < 4; ++i)
#pragma unroll
      for (int j = 0; j < 4; ++j)
#pragma unroll
        for (int r = 0; r < 4; ++r) {
          float e = acc[i][j][r] + biasv[j];
          float p = __shfl_xor(e, 1);            // lane pair = (i,g) of one unit
          float iv = odd ? p : e;
          float gv = odd ? e : p;
          float t = tanhf_(sigmoidf_(iv) * tanhf_(gv));
          if (!odd) {
            int row = wrow * 64 + i * 16 + qf * 4 + r;
            int unit = (n0 + wcol * 64 + j * 16 + m_) >> 1;
            Tq[(t0 + row) * 512 + unit] = q16(t);
          }
        }
  } else if (EMODE == 1 || EMODE == 2) {
#pragma unroll
    for (int i = 0; i < 4; ++i)
#pragma unroll
      for (int j = 0; j < 4; ++j)
#pragma unroll
        for (int r = 0; r < 4; ++r) {
          int row = wrow * 64 + i * 16 + qf * 4 + r;
          int unit = n0 + wcol * 64 + j * 16 + m_;
          size_t idx = (t0 + row) * 512 + (size_t)unit;
          float t = (float)Tq[idx] * (1.0f / 32768.0f);
          float h = sigmoidf_(acc[i][j][r] + biasv[j]) * t;
          if (EMODE == 1) Hf[idx] = h;
          else            Tq[idx] = q16(h);      // in-place over t
        }
  } else {
#pragma unroll
    for (int i = 0; i < 4; ++i)
#pragma unroll
      for (int j = 0; j < 4; ++j)
#pragma unroll
        for (int r = 0; r < 4; ++r) {
          int row = wrow * 64 + i * 16 + qf * 4 + r;
          int col = n0 + wcol * 64 + j * 16 + m_;
          float v = fmaxf(acc[i][j][r] + biasv[j], 0.0f);
          Out[(t0 + row) * 512 + (size_t)col] = v;
        }
  }
}

extern "C" void kernel_launch(void* const* d_in, const int* in_sizes, int n_in,
                              void* d_out, int out_size, void* d_ws, size_t ws_size,
                              hipStream_t stream) {
  (void)in_sizes; (void)n_in; (void)out_size; (void)ws_size;
  const int*   ids   = (const int*)d_in[0];
  const float* emb   = (const float*)d_in[1];
  const float* W0    = (const float*)d_in[2];
  // d_in[3] = W_hh0 unused (h_prev = 0)
  const float* bi0   = (const float*)d_in[4];
  const float* bh0   = (const float*)d_in[5];
  const float* W1    = (const float*)d_in[6];
  // d_in[7] = W_hh1 unused
  const float* bi1   = (const float*)d_in[8];
  const float* bh1   = (const float*)d_in[9];
  const float* WL    = (const float*)d_in[10];
  const float* blin  = (const float*)d_in[11];
  float* out = (float*)d_out;

  char* ws = (char*)d_ws;
  const size_t MB = 1024 * 1024;
  ushort_t* Wig0h = (ushort_t*)(ws);
  ushort_t* Wig0l = (ushort_t*)(ws + 1 * MB);
  ushort_t* Wo0h  = (ushort_t*)(ws + 2 * MB);
  ushort_t* Wo0l  = (ushort_t*)(ws + 2 * MB + 512 * 1024);
  ushort_t* Wig1h = (ushort_t*)(ws + 3 * MB);
  ushort_t* Wig1l = (ushort_t*)(ws + 4 * MB);
  ushort_t* Wo1h  = (ushort_t*)(ws + 5 * MB);
  ushort_t* Wo1l  = (ushort_t*)(ws + 5 * MB + 512 * 1024);
  ushort_t* WLh   = (ushort_t*)(ws + 6 * MB);
  ushort_t* WLl   = (ushort_t*)(ws + 6 * MB + 512 * 1024);
  float*    big0  = (float*)(ws + 7 * MB);
  float*    bo0   = (float*)(ws + 7 * MB + 4096);
  float*    big1  = (float*)(ws + 7 * MB + 8192);
  float*    bo1   = (float*)(ws + 7 * MB + 12288);
  short*    Tq    = (short*)(ws + 8 * MB);     // 64 MB: t (l0), t (l1), then h1
  float*    Hf    = (float*)(ws + 80 * MB);    // 128 MB: h0 fp32

  prep_kernel<<<7181, 256, 0, stream>>>(W0, bi0, bh0, W1, bi1, bh1, WL,
                                        Wig0h, Wig0l, Wo0h, Wo0l,
                                        Wig1h, Wig1l, Wo1h, Wo1l,
                                        WLh, WLl, big0, bo0, big1, bo1);
  // layer 0: A = emb rows gathered via ids
  gemm_kernel<0, 0><<<2048, 512, 0, stream>>>(emb, ids, Wig0h, Wig0l, big0,
                                              Tq, nullptr, nullptr, 3, 7);
  gemm_kernel<0, 1><<<1024, 512, 0, stream>>>(emb, ids, Wo0h, Wo0l, bo0,
                                              Tq, Hf, nullptr, 2, 3);
  // layer 1: A = h0 fp32
  gemm_kernel<0, 0><<<2048, 512, 0, stream>>>(Hf, nullptr, Wig1h, Wig1l, big1,
                                              Tq, nullptr, nullptr, 3, 7);
  gemm_kernel<0, 2><<<1024, 512, 0, stream>>>(Hf, nullptr, Wo1h, Wo1l, bo1,
                                              Tq, nullptr, nullptr, 2, 3);
  // linear: A = h1 int16
  gemm_kernel<1, 3><<<1024, 512, 0, stream>>>(Tq, nullptr, WLh, WLl, blin,
                                              nullptr, nullptr, out, 2, 3);
}

// Round 4
// 687.753 us; speedup vs baseline: 2.2047x; 2.2047x over previous
//
#include <hip/hip_runtime.h>
#include <stdint.h>

// LSTM2Encoder: x=emb[ids]; h0=lstm0(x); h1=lstm1(h0); out=relu(h1@Wlin^T+b)
// R2 skeleton (proven swizzles/epilogue) at fp16 single-product precision:
// error budget shows fp16 quant of A and B adds only ~1.3e-4 RMS per gate
// (threshold 2e-3), so the 3-product bf16 split was 3x over-engineered.
// A staged as single fp16 (24KB LDS -> 4 blocks/CU); layer-0 A gathered from
// prep-cast fp16 emb via per-lane ids pointers in global_load_lds.

typedef _Float16 half8 __attribute__((ext_vector_type(8)));
typedef __attribute__((ext_vector_type(4))) float float4v;
typedef __attribute__((ext_vector_type(4))) unsigned int uint4v;

__device__ __forceinline__ float sigmoidf_(float x) { return 1.0f / (1.0f + __expf(-x)); }
__device__ __forceinline__ float tanhf_(float x) { return 1.0f - 2.0f / (__expf(2.0f * x) + 1.0f); }

__device__ __forceinline__ void gl2lds16(const void* g, void* l) {
  __builtin_amdgcn_global_load_lds(
      (const __attribute__((address_space(1))) void*)g,
      (__attribute__((address_space(3))) void*)l, 16, 0, 0);
}

// ---------------- prep: emb->fp16; weights permuted+cast; biases folded ----
// W'[4j+g][k] = W[g*512+j][k]  (g in {i,f,g,o});  b'[4j+g] = b_ih[n]+b_hh[n]
__global__ __launch_bounds__(256) void prep_kernel(
    const float* __restrict__ emb,
    const float* __restrict__ W0, const float* __restrict__ bi0, const float* __restrict__ bh0,
    const float* __restrict__ W1, const float* __restrict__ bi1, const float* __restrict__ bh1,
    const float* __restrict__ WL,
    _Float16* __restrict__ Ef,
    _Float16* __restrict__ W0f, _Float16* __restrict__ W1f, _Float16* __restrict__ WLf,
    float* __restrict__ b0p, float* __restrict__ b1p)
{
  int id = blockIdx.x * 256 + threadIdx.x;
  if (id < 25731584) {                              // emb cast (50257 x 512)
    Ef[id] = (_Float16)emb[id];
  } else if (id < 26780160) {                       // W0 permute+cast
    int f = id - 25731584;
    int np = f >> 9, k = f & 511;
    int n = ((np & 3) << 9) | (np >> 2);
    W0f[f] = (_Float16)W0[n * 512 + k];
  } else if (id < 27828736) {                       // W1
    int f = id - 26780160;
    int np = f >> 9, k = f & 511;
    int n = ((np & 3) << 9) | (np >> 2);
    W1f[f] = (_Float16)W1[n * 512 + k];
  } else if (id < 28090880) {                       // WL (no permute)
    int f = id - 27828736;
    WLf[f] = (_Float16)WL[f];
  } else if (id < 28092928) {                       // b0 fold+permute
    int np = id - 28090880;
    int n = ((np & 3) << 9) | (np >> 2);
    b0p[np] = bi0[n] + bh0[n];
  } else if (id < 28094976) {                       // b1
    int np = id - 28092928;
    int n = ((np & 3) << 9) | (np >> 2);
    b1p[np] = bi1[n] + bh1[n];
  }
}

// ---------------- fused fp16 GEMM, 256x128 tile, BK=32 ---------------------
// MODE 0: LSTM layer  -> h = sig(o)*tanh(sig(i)*tanh(g)), write h fp16
// MODE 1: final linear -> out = relu(acc + bias), write fp32
template <int MODE>
__global__ __launch_bounds__(512, 4) void gemm_kernel(
    const _Float16* __restrict__ A, const int* __restrict__ ids,
    const _Float16* __restrict__ B, const float* __restrict__ bias,
    _Float16* __restrict__ Of, float* __restrict__ Out,
    int nbShift, int nbMask)
{
  __shared__ __align__(16) char smem[36864];        // K-loop 24KB; hT 34.8KB
  _Float16* sA = (_Float16*)smem;                   // 256 x 32
  _Float16* sB = (_Float16*)(smem + 16384);         // 128 x 32

  const int T = threadIdx.x;
  const int lane = T & 63;
  const int wv = T >> 6;
  const int wrow = wv >> 1, wcol = wv & 1;          // 4 x 2 wave grid
  const int mb = (int)blockIdx.x >> nbShift;
  const int nb = (int)blockIdx.x & nbMask;
  const size_t t0 = (size_t)mb * 256;
  const int n0 = nb * 128;

  // staging (R2-proven): thread T stages LDS chunk T (lane-contiguous 16B);
  // global k-quad XOR-swizzled by row so frag ds_read_b128 is 2-way (free).
  const int r0 = T >> 2;                            // 0..127
  const int qg = (T & 3) ^ ((r0 >> 1) & 3);
  size_t sr0 = t0 + r0, sr1 = t0 + 128 + r0;
  if (ids) { sr0 = (size_t)(unsigned)ids[sr0]; sr1 = (size_t)(unsigned)ids[sr1]; }
  const _Float16* gA0 = A + sr0 * 512 + qg * 8;
  const _Float16* gA1 = A + sr1 * 512 + qg * 8;
  const _Float16* gB  = B + (size_t)(n0 + r0) * 512 + qg * 8;

  // fragment read offsets (iter-invariant); un-swizzle with qs
  const int m_ = lane & 15, qf = lane >> 4;
  const int qs = qf ^ ((m_ >> 1) & 3);
  const int offA = wrow * 2048 + m_ * 32 + qs * 8;
  const int offB = wcol * 2048 + m_ * 32 + qs * 8;

  float4v acc[4][4];
#pragma unroll
  for (int i = 0; i < 4; ++i)
#pragma unroll
    for (int j = 0; j < 4; ++j)
      acc[i][j] = (float4v){0.f, 0.f, 0.f, 0.f};

  for (int it = 0; it < 16; ++it) {
    gl2lds16(gA0, sA + T * 8);                      // rows 0..127
    gl2lds16(gA1, sA + 4096 + T * 8);               // rows 128..255
    gl2lds16(gB,  sB + T * 8);
    gA0 += 32; gA1 += 32; gB += 32;
    __syncthreads();

    half8 a[4], b[4];
#pragma unroll
    for (int i = 0; i < 4; ++i) {
      a[i] = *(const half8*)(sA + offA + i * 512);
      b[i] = *(const half8*)(sB + offB + i * 512);
    }
#pragma unroll
    for (int i = 0; i < 4; ++i)
#pragma unroll
      for (int j = 0; j < 4; ++j)
        acc[i][j] = __builtin_amdgcn_mfma_f32_16x16x32_f16(a[i], b[j], acc[i][j], 0, 0, 0);
    __syncthreads();
  }

  float biasv[4];
#pragma unroll
  for (int j = 0; j < 4; ++j) biasv[j] = bias[n0 + wcol * 64 + j * 16 + m_];

  if (MODE == 0) {
    float* hT = (float*)smem;                       // 256 x 32, stride 34
    const bool b0 = (lane & 1) != 0;
    const bool b1 = (lane & 2) != 0;
    const int rowb = wrow * 64 + qf * 4 + (lane & 3);
    const int ub = wcol * 16 + (m_ >> 2);
#pragma unroll
    for (int i = 0; i < 4; ++i)
#pragma unroll
      for (int j = 0; j < 4; ++j) {
        // 4x4 lane<->reg transpose within each gate-quad (R2-proven): lane
        // ends holding gates i,g,o of one distinct row; f never used.
        float e0 = acc[i][j][0] + biasv[j];
        float e1 = acc[i][j][1] + biasv[j];
        float e2 = acc[i][j][2] + biasv[j];
        float e3 = acc[i][j][3] + biasv[j];
        float ta = __shfl_xor(b0 ? e0 : e1, 1);
        float tb = __shfl_xor(b0 ? e2 : e3, 1);
        float z0 = b0 ? ta : e0, z1 = b0 ? e1 : ta;
        float z2 = b0 ? tb : e2, z3 = b0 ? e3 : tb;
        float ua = __shfl_xor(b1 ? z0 : z2, 2);
        float ub_ = __shfl_xor(b1 ? z1 : z3, 2);
        float yi = b1 ? ua : z0;                    // gate i
        float yg = b1 ? z2 : ua;                    // gate g
        float yo = b1 ? z3 : ub_;                   // gate o
        float cc = sigmoidf_(yi) * tanhf_(yg);
        float hh = sigmoidf_(yo) * tanhf_(cc);
        hT[(rowb + i * 16) * 34 + ub + j * 4] = hh;
      }
    __syncthreads();
    const int tl = T >> 1, hf = T & 1;
    const float* src = hT + tl * 34 + hf * 16;
    union { _Float16 h[8]; uint4v v; } P0, P1;
#pragma unroll
    for (int e = 0; e < 8; ++e) {
      P0.h[e] = (_Float16)src[e];
      P1.h[e] = (_Float16)src[8 + e];
    }
    _Float16* dst = Of + (t0 + tl) * 512 + (size_t)(nb * 32) + hf * 16;
    *(uint4v*)dst = P0.v;
    *(uint4v*)(dst + 8) = P1.v;
  } else {
#pragma unroll
    for (int i = 0; i < 4; ++i)
#pragma unroll
      for (int j = 0; j < 4; ++j)
#pragma unroll
        for (int r = 0; r < 4; ++r) {
          float v = fmaxf(acc[i][j][r] + biasv[j], 0.0f);
          size_t row = t0 + wrow * 64 + i * 16 + qf * 4 + r;
          Out[row * 512 + (size_t)(n0 + wcol * 64 + j * 16 + m_)] = v;
        }
  }
}

extern "C" void kernel_launch(void* const* d_in, const int* in_sizes, int n_in,
                              void* d_out, int out_size, void* d_ws, size_t ws_size,
                              hipStream_t stream) {
  (void)in_sizes; (void)n_in; (void)out_size; (void)ws_size;
  const int*   ids   = (const int*)d_in[0];
  const float* emb   = (const float*)d_in[1];
  const float* W0    = (const float*)d_in[2];
  // d_in[3] = W_hh0 unused (h_prev = 0)
  const float* bi0   = (const float*)d_in[4];
  const float* bh0   = (const float*)d_in[5];
  const float* W1    = (const float*)d_in[6];
  // d_in[7] = W_hh1 unused
  const float* bi1   = (const float*)d_in[8];
  const float* bh1   = (const float*)d_in[9];
  const float* WL    = (const float*)d_in[10];
  const float* blin  = (const float*)d_in[11];
  float* out = (float*)d_out;

  char* ws = (char*)d_ws;
  const size_t MB = 1024 * 1024;
  _Float16* W0f = (_Float16*)(ws);                  // 2 MB
  _Float16* W1f = (_Float16*)(ws + 2 * MB);         // 2 MB
  _Float16* WLf = (_Float16*)(ws + 4 * MB);         // 0.5 MB
  float*    b0p = (float*)(ws + 4 * MB + 512 * 1024);
  float*    b1p = (float*)(ws + 4 * MB + 512 * 1024 + 8192);
  _Float16* Ef  = (_Float16*)(ws + 8 * MB);         // 51.5 MB (64 MB slot)
  _Float16* H1f = Ef;                               // Ef dead after layer 0
  _Float16* H0f = (_Float16*)(ws + 72 * MB);        // 64 MB
  // total ws use: 136 MB

  prep_kernel<<<109746, 256, 0, stream>>>(emb, W0, bi0, bh0, W1, bi1, bh1, WL,
                                          Ef, W0f, W1f, WLf, b0p, b1p);
  gemm_kernel<0><<<4096, 512, 0, stream>>>(Ef, ids, W0f, b0p, H0f, nullptr, 4, 15);
  gemm_kernel<0><<<4096, 512, 0, stream>>>(H0f, nullptr, W1f, b1p, H1f, nullptr, 4, 15);
  gemm_kernel<1><<<1024, 512, 0, stream>>>(H1f, nullptr, WLf, blin, nullptr, out, 2, 3);
}